// Round 17
// baseline (428.845 us; speedup 1.0000x reference)
//
#include <hip/hip_runtime.h>

#define H 256
#define NT 50000      // num task nodes
#define NEDGE 50000   // num edge nodes
#define NE 500000     // edges per edge-type

#define NBKT 391      // coarse buckets = ceil(50000/128), key>>7
#define NBLK 123      // edge chunks   = ceil(500000/4096)
#define CHUNK 4096
#define CAP 2816      // max bucket size guard

typedef __attribute__((ext_vector_type(8))) short short8_t;  // 8 bf16 (4 VGPR)
typedef __attribute__((ext_vector_type(4))) float f32x4;
typedef unsigned short u16;
typedef unsigned int u32;

__device__ __forceinline__ float b2f(u16 v) { return __uint_as_float((u32)v << 16); }
__device__ __forceinline__ u16 f2b(float f) {
    u32 u = __float_as_uint(f);
    u += 0x7FFFu + ((u >> 16) & 1u);
    return (u16)(u >> 16);
}

// ---- fp8 e4m3 (OCP) pack/unpack, HW cvt when available ----
__device__ __forceinline__ u32 f2fp8_1(float f) {
    u32 u = __float_as_uint(f);
    u32 s = (u >> 24) & 0x80u;
    float af = fabsf(f);
    if (af >= 448.f) return s | 0x7Eu;
    if (af < 0.015625f) {
        int m = (int)rintf(af * 512.0f);
        return s | (u32)m;
    }
    u32 au = __float_as_uint(af);
    u32 r = au + 0x7FFFFu + ((au >> 20) & 1u);
    int e = (int)(r >> 23) - 127;
    return s | (u32)(((e + 7) << 3) | ((r >> 20) & 7u));
}
__device__ __forceinline__ float fp82f_1(u32 b) {
    u32 s = (b & 0x80u) << 24;
    u32 em = b & 0x7Fu;
    float v;
    if (em >= 8) v = __uint_as_float((((em >> 3) + 120u) << 23) | ((em & 7u) << 20));
    else v = (float)em * 0.001953125f;
    return __uint_as_float(__float_as_uint(v) | s);
}
__device__ __forceinline__ u32 pk4_fp8(float a, float b, float c, float d) {
#if __has_builtin(__builtin_amdgcn_cvt_pk_fp8_f32)
    u32 r = 0;
    r = (u32)__builtin_amdgcn_cvt_pk_fp8_f32(a, b, (int)r, false);
    r = (u32)__builtin_amdgcn_cvt_pk_fp8_f32(c, d, (int)r, true);
    return r;
#else
    return f2fp8_1(a) | (f2fp8_1(b) << 8) | (f2fp8_1(c) << 16) | (f2fp8_1(d) << 24);
#endif
}
__device__ __forceinline__ float4 unpk4_fp8(u32 v) {
#if __has_builtin(__builtin_amdgcn_cvt_pk_f32_fp8)
    auto lo = __builtin_amdgcn_cvt_pk_f32_fp8(v, false);
    auto hi = __builtin_amdgcn_cvt_pk_f32_fp8(v, true);
    return make_float4(lo[0], lo[1], hi[0], hi[1]);
#else
    return make_float4(fp82f_1(v & 255u), fp82f_1((v >> 8) & 255u),
                       fp82f_1((v >> 16) & 255u), fp82f_1(v >> 24));
#endif
}

__device__ __forceinline__ const int* pick_list(
    int l, const int* a, const int* b, const int* c, const int* d, const int* e)
{ return (l == 0) ? a : (l == 1) ? b : (l == 2) ? c : (l == 3) ? d : e; }

// ---------------- encoder body (K1=64, fp32 input) — shared by combo kernels ----------------
__device__ __forceinline__ void enc_body(
    char* arena, int bid, const float* __restrict__ X,
    const u16* __restrict__ W1h, const u16* __restrict__ W1l, const float* __restrict__ b1,
    const u16* __restrict__ W2h, const u16* __restrict__ W2l, const float* __restrict__ b2,
    u16* __restrict__ out, u32* __restrict__ f8, int N)
{
    const int m0 = bid * 64;

    for (int i = threadIdx.x; i < 64 * 8; i += 256) {
        int r = i >> 3, c8 = i & 7;
        int gr = m0 + r; if (gr >= N) gr = N - 1;
        const float* xf = X + (size_t)gr * 64 + c8 * 8;
        float4 a = *(const float4*)xf;
        float4 b = *(const float4*)(xf + 4);
        uint4 v;
        v.x = (u32)f2b(a.x) | ((u32)f2b(a.y) << 16);
        v.y = (u32)f2b(a.z) | ((u32)f2b(a.w) << 16);
        v.z = (u32)f2b(b.x) | ((u32)f2b(b.y) << 16);
        v.w = (u32)f2b(b.z) | ((u32)f2b(b.w) << 16);
        u32 byte = (u32)(r * 128 + c8 * 16) ^ (u32)((r & 7) << 4);
        *(uint4*)(arena + byte) = v;
    }
    __syncthreads();

    const int wv = threadIdx.x >> 6, l = threadIdx.x & 63;
    const int li = l & 15, lk = l >> 4;

    f32x4 acc[4][4];
    #pragma unroll
    for (int i = 0; i < 4; i++)
        #pragma unroll
        for (int j = 0; j < 4; j++)
            acc[i][j] = (f32x4){0.f, 0.f, 0.f, 0.f};

    // layer 1 (K=64, 2 k-steps, pipelined)
    {
        short8_t whc[4], wlc[4];
        #pragma unroll
        for (int ni = 0; ni < 4; ni++) {
            const size_t wi = (size_t)((wv * 4 + ni) * 2) * 64 + l;
            whc[ni] = ((const short8_t*)W1h)[wi];
            wlc[ni] = ((const short8_t*)W1l)[wi];
        }
        #pragma unroll
        for (int ks = 0; ks < 2; ks++) {
            short8_t whn[4], wln[4];
            if (ks + 1 < 2) {
                #pragma unroll
                for (int ni = 0; ni < 4; ni++) {
                    const size_t wi = (size_t)((wv * 4 + ni) * 2 + ks + 1) * 64 + l;
                    whn[ni] = ((const short8_t*)W1h)[wi];
                    wln[ni] = ((const short8_t*)W1l)[wi];
                }
            }
            short8_t xb[4];
            #pragma unroll
            for (int mi = 0; mi < 4; mi++) {
                int m = mi * 16 + li;
                u32 byte = (u32)(m * 128 + (ks * 32 + lk * 8) * 2) ^ (u32)((m & 7) << 4);
                xb[mi] = *(const short8_t*)(arena + byte);
            }
            __builtin_amdgcn_s_setprio(1);
            #pragma unroll
            for (int ni = 0; ni < 4; ni++)
                #pragma unroll
                for (int mi = 0; mi < 4; mi++) {
                    acc[mi][ni] = __builtin_amdgcn_mfma_f32_16x16x32_bf16(wlc[ni], xb[mi], acc[mi][ni], 0, 0, 0);
                    acc[mi][ni] = __builtin_amdgcn_mfma_f32_16x16x32_bf16(whc[ni], xb[mi], acc[mi][ni], 0, 0, 0);
                }
            __builtin_amdgcn_s_setprio(0);
            if (ks + 1 < 2) {
                #pragma unroll
                for (int ni = 0; ni < 4; ni++) { whc[ni] = whn[ni]; wlc[ni] = wln[ni]; }
            }
        }
    }

    __syncthreads();

    #pragma unroll
    for (int ni = 0; ni < 4; ni++) {
        int c = wv * 64 + ni * 16 + lk * 4;
        float4 b4 = *(const float4*)(b1 + c);
        #pragma unroll
        for (int mi = 0; mi < 4; mi++) {
            int m = mi * 16 + li;
            float o0 = fmaxf(acc[mi][ni][0] + b4.x, 0.f);
            float o1 = fmaxf(acc[mi][ni][1] + b4.y, 0.f);
            float o2 = fmaxf(acc[mi][ni][2] + b4.z, 0.f);
            float o3 = fmaxf(acc[mi][ni][3] + b4.w, 0.f);
            u32 w0 = (u32)f2b(o0) | ((u32)f2b(o1) << 16);
            u32 w1 = (u32)f2b(o2) | ((u32)f2b(o3) << 16);
            u32 byte = (u32)(m * 512 + c * 2) ^ (u32)((m & 7) << 4);
            *(uint2*)(arena + byte) = make_uint2(w0, w1);
        }
    }
    __syncthreads();

    #pragma unroll
    for (int i = 0; i < 4; i++)
        #pragma unroll
        for (int j = 0; j < 4; j++)
            acc[i][j] = (f32x4){0.f, 0.f, 0.f, 0.f};

    // layer 2 (K=256, pipelined)
    {
        short8_t whc[4], wlc[4];
        #pragma unroll
        for (int ni = 0; ni < 4; ni++) {
            const size_t wi = (size_t)((wv * 4 + ni) * 8) * 64 + l;
            whc[ni] = ((const short8_t*)W2h)[wi];
            wlc[ni] = ((const short8_t*)W2l)[wi];
        }
        #pragma unroll
        for (int ks = 0; ks < 8; ks++) {
            short8_t whn[4], wln[4];
            if (ks + 1 < 8) {
                #pragma unroll
                for (int ni = 0; ni < 4; ni++) {
                    const size_t wi = (size_t)((wv * 4 + ni) * 8 + ks + 1) * 64 + l;
                    whn[ni] = ((const short8_t*)W2h)[wi];
                    wln[ni] = ((const short8_t*)W2l)[wi];
                }
            }
            short8_t xb[4];
            #pragma unroll
            for (int mi = 0; mi < 4; mi++) {
                int m = mi * 16 + li;
                u32 byte = (u32)(m * 512 + (ks * 32 + lk * 8) * 2) ^ (u32)((m & 7) << 4);
                xb[mi] = *(const short8_t*)(arena + byte);
            }
            __builtin_amdgcn_s_setprio(1);
            #pragma unroll
            for (int ni = 0; ni < 4; ni++)
                #pragma unroll
                for (int mi = 0; mi < 4; mi++) {
                    acc[mi][ni] = __builtin_amdgcn_mfma_f32_16x16x32_bf16(wlc[ni], xb[mi], acc[mi][ni], 0, 0, 0);
                    acc[mi][ni] = __builtin_amdgcn_mfma_f32_16x16x32_bf16(whc[ni], xb[mi], acc[mi][ni], 0, 0, 0);
                }
            __builtin_amdgcn_s_setprio(0);
            if (ks + 1 < 8) {
                #pragma unroll
                for (int ni = 0; ni < 4; ni++) { whc[ni] = whn[ni]; wlc[ni] = wln[ni]; }
            }
        }
    }

    __syncthreads();
    #pragma unroll
    for (int ni = 0; ni < 4; ni++) {
        int c = wv * 64 + ni * 16 + lk * 4;
        float4 b4 = *(const float4*)(b2 + c);
        #pragma unroll
        for (int mi = 0; mi < 4; mi++) {
            int m = mi * 16 + li;
            float o0 = fmaxf(acc[mi][ni][0] + b4.x, 0.f);
            float o1 = fmaxf(acc[mi][ni][1] + b4.y, 0.f);
            float o2 = fmaxf(acc[mi][ni][2] + b4.z, 0.f);
            float o3 = fmaxf(acc[mi][ni][3] + b4.w, 0.f);
            u32 w0 = (u32)f2b(o0) | ((u32)f2b(o1) << 16);
            u32 w1 = (u32)f2b(o2) | ((u32)f2b(o3) << 16);
            u32 byte = (u32)(m * 512 + c * 2) ^ (u32)((m & 7) << 4);
            *(uint2*)(arena + byte) = make_uint2(w0, w1);
        }
    }
    __syncthreads();
    for (int i = threadIdx.x; i < 64 * 32; i += 256) {
        int r = i >> 5, c8 = i & 31;
        int m = m0 + r;
        if (m < N) {
            u32 byte = (u32)(r * 512 + c8 * 16) ^ (u32)((r & 7) << 4);
            uint4 v = *(const uint4*)(arena + byte);
            *(uint4*)(out + (size_t)m * H + c8 * 8) = v;
            u32 p0 = pk4_fp8(b2f((u16)(v.x & 0xFFFF)), b2f((u16)(v.x >> 16)),
                             b2f((u16)(v.y & 0xFFFF)), b2f((u16)(v.y >> 16)));
            u32 p1 = pk4_fp8(b2f((u16)(v.z & 0xFFFF)), b2f((u16)(v.z >> 16)),
                             b2f((u16)(v.w & 0xFFFF)), b2f((u16)(v.w >> 16)));
            *(uint2*)(f8 + (size_t)m * 64 + c8 * 2) = make_uint2(p0, p1);
        }
    }
}

// ---------------- combo: partition ∥ task encoder ----------------
__global__ __launch_bounds__(256) void part_enc(
    const int* __restrict__ k0, const int* __restrict__ k1, const int* __restrict__ k2,
    const int* __restrict__ k3, const int* __restrict__ k4,
    const int* __restrict__ v0, const int* __restrict__ v1, const int* __restrict__ v2,
    const int* __restrict__ v3, const int* __restrict__ v4,
    const int* __restrict__ starts, int* __restrict__ csr,
    const float* __restrict__ X,
    const u16* __restrict__ W1h, const u16* __restrict__ W1l, const float* __restrict__ b1,
    const u16* __restrict__ W2h, const u16* __restrict__ W2l, const float* __restrict__ b2,
    u16* __restrict__ out, u32* __restrict__ f8, int N, int nCSR)
{
    __shared__ char arena[32768];
    if ((int)blockIdx.x >= nCSR) {
        enc_body(arena, blockIdx.x - nCSR, X, W1h, W1l, b1, W2h, W2l, b2, out, f8, N);
        return;
    }
    u32* ent = (u32*)arena;
    u16* ebk = (u16*)(arena + 16384);
    int* cnt  = (int*)(arena + 24576);
    int* loff = cnt + NBKT;
    int* cur  = loff + NBKT;
    int* gst  = cur + NBKT;
    int* buf  = (int*)(arena + 24576 + 4 * 4 * NBKT);
    int p = blockIdx.x;
    int l = p / NBLK, blk = p % NBLK;
    int t = threadIdx.x;
    const int* k = pick_list(l, k0, k1, k2, k3, k4);
    const int* v = pick_list(l, v0, v1, v2, v3, v4);
    const int* st = starts + ((size_t)l * NBLK + blk) * NBKT;
    for (int i = t; i < NBKT; i += 256) { cnt[i] = 0; gst[i] = st[i]; }
    __syncthreads();
    int e0 = blk * CHUNK;
    u32 ep[16]; int eb[16];
    #pragma unroll
    for (int j = 0; j < 16; j++) {
        int e = e0 + j * 256 + t;
        if (e < NE) {
            int key = k[e];
            eb[j] = key >> 7;
            ep[j] = ((u32)(key & 127) << 16) | (u32)v[e];
            atomicAdd(&cnt[eb[j]], 1);
        } else eb[j] = -1;
    }
    __syncthreads();
    int b0 = t * 2;
    int c0 = (b0 < NBKT) ? cnt[b0] : 0;
    int c1 = (b0 + 1 < NBKT) ? cnt[b0 + 1] : 0;
    int s = c0 + c1;
    buf[t] = s; __syncthreads();
    for (int stp = 1; stp < 256; stp <<= 1) {
        int x = (t >= stp) ? buf[t - stp] : 0; __syncthreads();
        buf[t] += x; __syncthreads();
    }
    int run = buf[t] - s;
    if (b0 < NBKT)     { loff[b0] = run;          cur[b0] = run; }
    if (b0 + 1 < NBKT) { loff[b0 + 1] = run + c0; cur[b0 + 1] = run + c0; }
    __syncthreads();
    #pragma unroll
    for (int j = 0; j < 16; j++) {
        if (eb[j] >= 0) {
            int q = atomicAdd(&cur[eb[j]], 1);
            ent[q] = ep[j]; ebk[q] = (u16)eb[j];
        }
    }
    __syncthreads();
    int nv = min(CHUNK, NE - e0);
    int* c = csr + (size_t)l * NE;
    for (int i = t; i < nv; i += 256) {
        int b = ebk[i];
        c[gst[b] + (i - loff[b])] = (int)ent[i];
    }
}

// ---------------- combo: bucket_csr ∥ edge encoder ----------------
__global__ __launch_bounds__(256) void buck_enc(
    const int* __restrict__ bases, int* __restrict__ csr, int* __restrict__ off,
    const float* __restrict__ X,
    const u16* __restrict__ W1h, const u16* __restrict__ W1l, const float* __restrict__ b1,
    const u16* __restrict__ W2h, const u16* __restrict__ W2l, const float* __restrict__ b2,
    u16* __restrict__ out, u32* __restrict__ f8, int N, int nCSR)
{
    __shared__ char arena[32768];
    if ((int)blockIdx.x >= nCSR) {
        enc_body(arena, blockIdx.x - nCSR, X, W1h, W1l, b1, W2h, W2l, b2, out, f8, N);
        return;
    }
    int* seg  = (int*)arena;
    int* hist = (int*)(arena + 11264);
    int* scn  = hist + 128;
    int p = blockIdx.x;
    int l = p / NBKT, b = p % NBKT;
    int t = threadIdx.x;
    int base = bases[l * (NBKT + 1) + b];
    int end  = bases[l * (NBKT + 1) + b + 1];
    int sz = end - base; if (sz > CAP) sz = CAP;
    int* c = csr + (size_t)l * NE;
    for (int i = t; i < sz; i += 256) seg[i] = c[base + i];
    if (t < 128) hist[t] = 0;
    __syncthreads();
    for (int i = t; i < sz; i += 256) atomicAdd(&hist[seg[i] >> 16], 1);
    __syncthreads();
    if (t < 128) scn[t] = hist[t];
    __syncthreads();
    for (int st = 1; st < 128; st <<= 1) {
        int v = 0;
        if (t < 128 && t >= st) v = scn[t - st];
        __syncthreads();
        if (t < 128) scn[t] += v;
        __syncthreads();
    }
    if (t < 128) {
        int key = b * 128 + t;
        int excl = scn[t] - hist[t];
        if (key < NT) off[l * (NT + 1) + key] = base + excl;
        hist[t] = excl;
    }
    if (b == 0 && t == 128) off[l * (NT + 1) + NT] = NE;
    __syncthreads();
    for (int i = t; i < sz; i += 256) {
        int u = seg[i];
        int q = atomicAdd(&hist[u >> 16], 1);
        c[base + q] = u & 0xFFFF;
    }
}

// ---------------- GNN fused 2-layer MLP (K1=256, fp8 queue fuse) ----------------
template<int K1>
__global__ __launch_bounds__(256) void fused_mlp(
    const u16* __restrict__ X, const u32* __restrict__ Q8,
    const u16* __restrict__ W1h, const u16* __restrict__ W1l, const float* __restrict__ b1,
    const u16* __restrict__ W2h, const u16* __restrict__ W2l, const float* __restrict__ b2,
    u16* __restrict__ out, u32* __restrict__ f8,
    int N, float s2)
{
    __shared__ u16 lds[64 * 256];
    const int m0 = blockIdx.x * 64;

    constexpr int RCH = K1 / 8;
    for (int i = threadIdx.x; i < 64 * RCH; i += 256) {
        int r = i / RCH, c8 = i % RCH;
        int gr = m0 + r; if (gr >= N) gr = N - 1;
        uint4 v = *(const uint4*)(X + (size_t)gr * K1 + c8 * 8);
        u32 byte = (u32)(r * (K1 * 2) + c8 * 16) ^ (u32)((r & 7) << 4);
        *(uint4*)((char*)lds + byte) = v;
    }
    __syncthreads();

    const int wv = threadIdx.x >> 6, l = threadIdx.x & 63;
    const int li = l & 15, lk = l >> 4;

    f32x4 acc[4][4];
    #pragma unroll
    for (int i = 0; i < 4; i++)
        #pragma unroll
        for (int j = 0; j < 4; j++)
            acc[i][j] = (f32x4){0.f, 0.f, 0.f, 0.f};

    {
        constexpr int KS = K1 / 32;
        short8_t whc[4], wlc[4];
        #pragma unroll
        for (int ni = 0; ni < 4; ni++) {
            const size_t wi = (size_t)((wv * 4 + ni) * KS) * 64 + l;
            whc[ni] = ((const short8_t*)W1h)[wi];
            wlc[ni] = ((const short8_t*)W1l)[wi];
        }
        #pragma unroll
        for (int ks = 0; ks < KS; ks++) {
            short8_t whn[4], wln[4];
            if (ks + 1 < KS) {
                #pragma unroll
                for (int ni = 0; ni < 4; ni++) {
                    const size_t wi = (size_t)((wv * 4 + ni) * KS + ks + 1) * 64 + l;
                    whn[ni] = ((const short8_t*)W1h)[wi];
                    wln[ni] = ((const short8_t*)W1l)[wi];
                }
            }
            short8_t xb[4];
            #pragma unroll
            for (int mi = 0; mi < 4; mi++) {
                int m = mi * 16 + li;
                u32 byte = (u32)(m * (K1 * 2) + (ks * 32 + lk * 8) * 2) ^ (u32)((m & 7) << 4);
                xb[mi] = *(const short8_t*)((const char*)lds + byte);
            }
            __builtin_amdgcn_s_setprio(1);
            #pragma unroll
            for (int ni = 0; ni < 4; ni++)
                #pragma unroll
                for (int mi = 0; mi < 4; mi++) {
                    acc[mi][ni] = __builtin_amdgcn_mfma_f32_16x16x32_bf16(wlc[ni], xb[mi], acc[mi][ni], 0, 0, 0);
                    acc[mi][ni] = __builtin_amdgcn_mfma_f32_16x16x32_bf16(whc[ni], xb[mi], acc[mi][ni], 0, 0, 0);
                }
            __builtin_amdgcn_s_setprio(0);
            if (ks + 1 < KS) {
                #pragma unroll
                for (int ni = 0; ni < 4; ni++) { whc[ni] = whn[ni]; wlc[ni] = wln[ni]; }
            }
        }
    }

    __syncthreads();

    #pragma unroll
    for (int ni = 0; ni < 4; ni++) {
        int c = wv * 64 + ni * 16 + lk * 4;
        float4 b4 = *(const float4*)(b1 + c);
        #pragma unroll
        for (int mi = 0; mi < 4; mi++) {
            int m = mi * 16 + li;
            float o0 = fmaxf(acc[mi][ni][0] + b4.x, 0.f);
            float o1 = fmaxf(acc[mi][ni][1] + b4.y, 0.f);
            float o2 = fmaxf(acc[mi][ni][2] + b4.z, 0.f);
            float o3 = fmaxf(acc[mi][ni][3] + b4.w, 0.f);
            int gm = m0 + m; if (gm >= N) gm = N - 1;
            float4 qf = unpk4_fp8(Q8[(size_t)gm * 64 + (c >> 2)]);
            o0 = fmaf(s2, qf.x, o0);
            o1 = fmaf(s2, qf.y, o1);
            o2 = fmaf(s2, qf.z, o2);
            o3 = fmaf(s2, qf.w, o3);
            u32 w0 = (u32)f2b(o0) | ((u32)f2b(o1) << 16);
            u32 w1 = (u32)f2b(o2) | ((u32)f2b(o3) << 16);
            u32 byte = (u32)(m * 512 + c * 2) ^ (u32)((m & 7) << 4);
            *(uint2*)((char*)lds + byte) = make_uint2(w0, w1);
        }
    }
    __syncthreads();

    #pragma unroll
    for (int i = 0; i < 4; i++)
        #pragma unroll
        for (int j = 0; j < 4; j++)
            acc[i][j] = (f32x4){0.f, 0.f, 0.f, 0.f};

    {
        short8_t whc[4], wlc[4];
        #pragma unroll
        for (int ni = 0; ni < 4; ni++) {
            const size_t wi = (size_t)((wv * 4 + ni) * 8) * 64 + l;
            whc[ni] = ((const short8_t*)W2h)[wi];
            wlc[ni] = ((const short8_t*)W2l)[wi];
        }
        #pragma unroll
        for (int ks = 0; ks < 8; ks++) {
            short8_t whn[4], wln[4];
            if (ks + 1 < 8) {
                #pragma unroll
                for (int ni = 0; ni < 4; ni++) {
                    const size_t wi = (size_t)((wv * 4 + ni) * 8 + ks + 1) * 64 + l;
                    whn[ni] = ((const short8_t*)W2h)[wi];
                    wln[ni] = ((const short8_t*)W2l)[wi];
                }
            }
            short8_t xb[4];
            #pragma unroll
            for (int mi = 0; mi < 4; mi++) {
                int m = mi * 16 + li;
                u32 byte = (u32)(m * 512 + (ks * 32 + lk * 8) * 2) ^ (u32)((m & 7) << 4);
                xb[mi] = *(const short8_t*)((const char*)lds + byte);
            }
            __builtin_amdgcn_s_setprio(1);
            #pragma unroll
            for (int ni = 0; ni < 4; ni++)
                #pragma unroll
                for (int mi = 0; mi < 4; mi++) {
                    acc[mi][ni] = __builtin_amdgcn_mfma_f32_16x16x32_bf16(wlc[ni], xb[mi], acc[mi][ni], 0, 0, 0);
                    acc[mi][ni] = __builtin_amdgcn_mfma_f32_16x16x32_bf16(whc[ni], xb[mi], acc[mi][ni], 0, 0, 0);
                }
            __builtin_amdgcn_s_setprio(0);
            if (ks + 1 < 8) {
                #pragma unroll
                for (int ni = 0; ni < 4; ni++) { whc[ni] = whn[ni]; wlc[ni] = wln[ni]; }
            }
        }
    }

    __syncthreads();
    #pragma unroll
    for (int ni = 0; ni < 4; ni++) {
        int c = wv * 64 + ni * 16 + lk * 4;
        float4 b4 = *(const float4*)(b2 + c);
        #pragma unroll
        for (int mi = 0; mi < 4; mi++) {
            int m = mi * 16 + li;
            float o0 = fmaxf(acc[mi][ni][0] + b4.x, 0.f);
            float o1 = fmaxf(acc[mi][ni][1] + b4.y, 0.f);
            float o2 = fmaxf(acc[mi][ni][2] + b4.z, 0.f);
            float o3 = fmaxf(acc[mi][ni][3] + b4.w, 0.f);
            u32 w0 = (u32)f2b(o0) | ((u32)f2b(o1) << 16);
            u32 w1 = (u32)f2b(o2) | ((u32)f2b(o3) << 16);
            u32 byte = (u32)(m * 512 + c * 2) ^ (u32)((m & 7) << 4);
            *(uint2*)((char*)lds + byte) = make_uint2(w0, w1);
        }
    }
    __syncthreads();
    for (int i = threadIdx.x; i < 64 * 32; i += 256) {
        int r = i >> 5, c8 = i & 31;
        int m = m0 + r;
        if (m < N) {
            u32 byte = (u32)(r * 512 + c8 * 16) ^ (u32)((r & 7) << 4);
            uint4 v = *(const uint4*)((const char*)lds + byte);
            *(uint4*)(out + (size_t)m * H + c8 * 8) = v;
            u32 p0 = pk4_fp8(b2f((u16)(v.x & 0xFFFF)), b2f((u16)(v.x >> 16)),
                             b2f((u16)(v.y & 0xFFFF)), b2f((u16)(v.y >> 16)));
            u32 p1 = pk4_fp8(b2f((u16)(v.z & 0xFFFF)), b2f((u16)(v.z >> 16)),
                             b2f((u16)(v.w & 0xFFFF)), b2f((u16)(v.w >> 16)));
            *(uint2*)(f8 + (size_t)m * 64 + c8 * 2) = make_uint2(p0, p1);
        }
    }
}

// W [K][256] fp32 -> packed fragment-order hi/lo bf16 mirrors
__global__ __launch_bounds__(256) void wt_pack(
    const float* __restrict__ s0, const float* __restrict__ s1,
    const float* __restrict__ s2, const float* __restrict__ s3,
    const float* __restrict__ s4, const float* __restrict__ s5,
    u16* __restrict__ arena)
{
    const int li = blockIdx.y;
    const int K = (li == 0 || li == 4) ? 64 : 256;
    const int offs[6] = {0, 32768, 163840, 294912, 425984, 458752};
    int n = K * 256;
    int i = blockIdx.x * 256 + threadIdx.x;
    if (i >= n) return;
    const float* W = (li == 0) ? s0 : (li == 1) ? s1 : (li == 2) ? s2
                   : (li == 3) ? s3 : (li == 4) ? s4 : s5;
    u16* hi = arena + offs[li];
    u16* lo = hi + n;
    int k = i >> 8, c = i & 255;
    float u = W[i];
    u32 b = __float_as_uint(u);
    float r = u - __uint_as_float(b & 0xFFFF0000u);
    int lane = ((k >> 3) & 3) * 16 + (c & 15);
    size_t idx = ((size_t)((c >> 4) * (K >> 5) + (k >> 5)) * 64 + lane) * 8 + (k & 7);
    hi[idx] = (u16)(b >> 16);
    lo[idx] = f2b(r);
}

// ---------------- CSR build P1/P2 ----------------
__global__ __launch_bounds__(256) void hist_kernel(
    const int* __restrict__ k0, const int* __restrict__ k1, const int* __restrict__ k2,
    const int* __restrict__ k3, const int* __restrict__ k4, int* __restrict__ counts)
{
    __shared__ int h[NBKT];
    int l = blockIdx.y;
    const int* k = pick_list(l, k0, k1, k2, k3, k4);
    for (int i = threadIdx.x; i < NBKT; i += 256) h[i] = 0;
    __syncthreads();
    int e0 = blockIdx.x * CHUNK;
    for (int i = threadIdx.x; i < CHUNK; i += 256) {
        int e = e0 + i;
        if (e < NE) atomicAdd(&h[k[e] >> 7], 1);
    }
    __syncthreads();
    int* out = counts + ((size_t)l * NBLK + blockIdx.x) * NBKT;
    for (int i = threadIdx.x; i < NBKT; i += 256) out[i] = h[i];
}

__global__ __launch_bounds__(256) void scan_buckets(
    const int* __restrict__ counts, int* __restrict__ starts, int* __restrict__ bases)
{
    __shared__ int buf[256];
    int l = blockIdx.x, t = threadIdx.x;
    const int* cl = counts + (size_t)l * NBLK * NBKT;
    int* sl = starts + (size_t)l * NBLK * NBKT;
    int b0 = t * 2;
    int totloc[2];
    int s = 0;
    #pragma unroll
    for (int j = 0; j < 2; j++) {
        int b = b0 + j, v = 0;
        if (b < NBKT) for (int k = 0; k < NBLK; k++) v += cl[k * NBKT + b];
        totloc[j] = v; s += v;
    }
    buf[t] = s; __syncthreads();
    for (int st = 1; st < 256; st <<= 1) {
        int v = (t >= st) ? buf[t - st] : 0; __syncthreads();
        buf[t] += v; __syncthreads();
    }
    int run = buf[t] - s;
    #pragma unroll
    for (int j = 0; j < 2; j++) {
        int b = b0 + j;
        if (b < NBKT) {
            bases[l * (NBKT + 1) + b] = run;
            int p = run;
            for (int k = 0; k < NBLK; k++) { sl[k * NBKT + b] = p; p += cl[k * NBKT + b]; }
            run += totloc[j];
        }
    }
    if (t == 255) bases[l * (NBKT + 1) + NBKT] = NE;
}

// ---------------- gathers (fp8 src, 8-deep pipeline) ----------------
// queue conv: S8 = fp8(segsum); F = T + s2*segsum (bf16)
__global__ __launch_bounds__(256) void gather_q_f8(
    const u32* __restrict__ src, const int* __restrict__ csr,
    const int* __restrict__ off, const u16* __restrict__ baseT,
    u32* __restrict__ S8out, u16* __restrict__ fuseOut, float s2, int N)
{
    int r = (blockIdx.x * 256 + threadIdx.x) >> 6;
    int lane = threadIdx.x & 63;
    if (r >= N) return;
    int o0 = off[r];
    int d  = off[r + 1] - o0;
    float4 acc = {0.f, 0.f, 0.f, 0.f};
    int j = 0;
    for (; j + 8 <= d; j += 8) {
        u32 w[8];
        #pragma unroll
        for (int q = 0; q < 8; q++)
            w[q] = src[(size_t)csr[o0 + j + q] * 64 + lane];
        #pragma unroll
        for (int q = 0; q < 8; q++) {
            float4 f = unpk4_fp8(w[q]);
            acc.x += f.x; acc.y += f.y; acc.z += f.z; acc.w += f.w;
        }
    }
    for (; j < d; j++) {
        float4 f = unpk4_fp8(src[(size_t)csr[o0 + j] * 64 + lane]);
        acc.x += f.x; acc.y += f.y; acc.z += f.z; acc.w += f.w;
    }
    S8out[(size_t)r * 64 + lane] = pk4_fp8(acc.x, acc.y, acc.z, acc.w);
    ushort4 b = ((const ushort4*)(baseT + (size_t)r * H))[lane];
    ushort4 pk;
    pk.x = f2b(fmaf(s2, acc.x, b2f(b.x)));
    pk.y = f2b(fmaf(s2, acc.y, b2f(b.y)));
    pk.z = f2b(fmaf(s2, acc.z, b2f(b.z)));
    pk.w = f2b(fmaf(s2, acc.w, b2f(b.w)));
    ((ushort4*)(fuseOut + (size_t)r * H))[lane] = pk;
}

// fused type-conv + affinity-t with INTERLEAVED dual-list pipeline
__global__ __launch_bounds__(256) void gather_task2(
    const u32* __restrict__ M1s, const int* __restrict__ csr1, const int* __restrict__ off1,
    const u32* __restrict__ M2s, const int* __restrict__ csr2, const int* __restrict__ off2,
    const u16* __restrict__ T, u16* __restrict__ Sout, u32* __restrict__ M3out, int N)
{
    int r = (blockIdx.x * 256 + threadIdx.x) >> 6;
    int lane = threadIdx.x & 63;
    if (r >= N) return;

    int o1 = off1[r], d1 = off1[r + 1] - o1;
    int o2 = off2[r], d2 = off2[r + 1] - o2;
    int tot = d1 + d2;
    float4 a1 = {0.f, 0.f, 0.f, 0.f};
    float4 a2 = {0.f, 0.f, 0.f, 0.f};

    for (int base = 0; base < tot; base += 8) {
        u32 w[8];
        #pragma unroll
        for (int q = 0; q < 8; q++) {
            int idx = base + q;
            if (idx < d1)       w[q] = M1s[(size_t)csr1[o1 + idx] * 64 + lane];
            else if (idx < tot) w[q] = M2s[(size_t)csr2[o2 + idx - d1] * 64 + lane];
        }
        #pragma unroll
        for (int q = 0; q < 8; q++) {
            int idx = base + q;
            if (idx >= tot) break;                       // wave-uniform
            float4 f = unpk4_fp8(w[q]);
            if (idx < d1) { a1.x += f.x; a1.y += f.y; a1.z += f.z; a1.w += f.w; }
            else          { a2.x += f.x; a2.y += f.y; a2.z += f.z; a2.w += f.w; }
        }
    }
    float s1 = 0.3f / (float)max(d1, 1);
    float s2 = 0.3f / (float)max(d2, 1);
    ushort4 b = ((const ushort4*)(T + (size_t)r * H))[lane];
    float f0 = fmaf(s1, a1.x, b2f(b.x)), f1 = fmaf(s1, a1.y, b2f(b.y));
    float f2 = fmaf(s1, a1.z, b2f(b.z)), f3 = fmaf(s1, a1.w, b2f(b.w));
    M3out[(size_t)r * 64 + lane] = pk4_fp8(f0, f1, f2, f3);
    ushort4 pk;
    pk.x = f2b(fmaf(s2, a2.x, f0)); pk.y = f2b(fmaf(s2, a2.y, f1));
    pk.z = f2b(fmaf(s2, a2.z, f2)); pk.w = f2b(fmaf(s2, a2.w, f3));
    ((ushort4*)(Sout + (size_t)r * H))[lane] = pk;
}

__global__ __launch_bounds__(256) void gather_mean_f8(
    const u32* __restrict__ src, const int* __restrict__ csr, const int* __restrict__ off,
    const u16* __restrict__ base, u16* __restrict__ dst, u32* __restrict__ m8,
    float alpha, int N)
{
    int r = (blockIdx.x * 256 + threadIdx.x) >> 6;
    int lane = threadIdx.x & 63;
    if (r >= N) return;
    int o0 = off[r];
    int d  = off[r + 1] - o0;
    float4 acc = {0.f, 0.f, 0.f, 0.f};
    int j = 0;
    for (; j + 8 <= d; j += 8) {
        u32 w[8];
        #pragma unroll
        for (int q = 0; q < 8; q++)
            w[q] = src[(size_t)csr[o0 + j + q] * 64 + lane];
        #pragma unroll
        for (int q = 0; q < 8; q++) {
            float4 f = unpk4_fp8(w[q]);
            acc.x += f.x; acc.y += f.y; acc.z += f.z; acc.w += f.w;
        }
    }
    for (; j < d; j++) {
        float4 f = unpk4_fp8(src[(size_t)csr[o0 + j] * 64 + lane]);
        acc.x += f.x; acc.y += f.y; acc.z += f.z; acc.w += f.w;
    }
    float s = alpha / (float)max(d, 1);
    ushort4 b = ((const ushort4*)(base + (size_t)r * H))[lane];
    float o0f = fmaf(s, acc.x, b2f(b.x));
    float o1f = fmaf(s, acc.y, b2f(b.y));
    float o2f = fmaf(s, acc.z, b2f(b.z));
    float o3f = fmaf(s, acc.w, b2f(b.w));
    ushort4 pk;
    pk.x = f2b(o0f); pk.y = f2b(o1f); pk.z = f2b(o2f); pk.w = f2b(o3f);
    ((ushort4*)(dst + (size_t)r * H))[lane] = pk;
    if (m8) m8[(size_t)r * 64 + lane] = pk4_fp8(o0f, o1f, o2f, o3f);
}

// ---------------- reductions / head (parallelized) ----------------
__global__ __launch_bounds__(256) void colsum_slots(
    const u16* __restrict__ embA, const u16* __restrict__ embB,
    float* __restrict__ part, int N)
{
    int blk = blockIdx.x;
    const u16* emb = (blk < 256) ? embA : embB;
    int rb = blk & 255;
    int c = threadIdx.x;
    float s = 0.f;
    for (int r = rb; r < N; r += 256)
        s += b2f(emb[(size_t)r * H + c]);
    part[(size_t)blk * H + c] = s;
}

__global__ __launch_bounds__(256) void head_comb(
    const float* __restrict__ part, float invNT, float invNE,
    const float* __restrict__ ta_w, const float* __restrict__ ta_b,
    const float* __restrict__ ea_w, const float* __restrict__ ea_b,
    float* __restrict__ comb)
{
    __shared__ float mean[H];
    __shared__ float red[32][8];
    int blk = blockIdx.x;
    int side = blk >> 3;
    int c0 = (blk & 7) * 32;
    int t = threadIdx.x;
    const float* p = part + (side ? (size_t)256 * H : 0);
    float s = 0.f;
    for (int b = 0; b < 256; b++) s += p[(size_t)b * H + t];
    mean[t] = s * (side ? invNE : invNT);
    __syncthreads();
    const float* W = side ? ea_w : ta_w;
    const float* bb = side ? ea_b : ta_b;
    int c = t & 31, g = t >> 5;
    float acc = 0.f;
    for (int k = g * 32; k < g * 32 + 32; k++)
        acc += mean[k] * W[k * H + (c0 + c)];
    red[c][g] = acc;
    __syncthreads();
    if (t < 32) {
        float v = 0.f;
        #pragma unroll
        for (int g2 = 0; g2 < 8; g2++) v += red[t][g2];
        comb[side * H + c0 + t] = fmaxf(v + bb[c0 + t], 0.f);
    }
}

__global__ __launch_bounds__(256) void head_hid(
    const float* __restrict__ comb, const float* __restrict__ ow1,
    const float* __restrict__ ob1, float* __restrict__ hid)
{
    __shared__ float cb[2 * H];
    __shared__ float red[32][8];
    int c0 = blockIdx.x * 32;
    int t = threadIdx.x;
    cb[t] = comb[t];
    cb[t + H] = comb[t + H];
    __syncthreads();
    int c = t & 31, g = t >> 5;
    float acc = 0.f;
    for (int k = g * 64; k < g * 64 + 64; k++)
        acc += cb[k] * ow1[k * H + (c0 + c)];
    red[c][g] = acc;
    __syncthreads();
    if (t < 32) {
        float v = 0.f;
        #pragma unroll
        for (int g2 = 0; g2 < 8; g2++) v += red[t][g2];
        hid[c0 + t] = fmaxf(v + ob1[c0 + t], 0.f);
    }
}

__global__ __launch_bounds__(256) void head_out(
    const float* __restrict__ hid, const float* __restrict__ ow2,
    const float* __restrict__ ob2, float* __restrict__ out)
{
    __shared__ float hb[H];
    __shared__ float red[32][8];
    int c0 = blockIdx.x * 32;
    int t = threadIdx.x;
    hb[t] = hid[t];
    __syncthreads();
    int c = t & 31, g = t >> 5;
    float acc = 0.f;
    for (int k = g * 32; k < g * 32 + 32; k++)
        acc += hb[k] * ow2[k * H + (c0 + c)];
    red[c][g] = acc;
    __syncthreads();
    if (t < 32) {
        float v = 0.f;
        #pragma unroll
        for (int g2 = 0; g2 < 8; g2++) v += red[t][g2];
        out[c0 + t] = v + ob2[c0 + t];
    }
}

extern "C" void kernel_launch(void* const* d_in, const int* in_sizes, int n_in,
                              void* d_out, int out_size, void* d_ws, size_t ws_size,
                              hipStream_t stream) {
    const float* tf  = (const float*)d_in[0];
    const float* ef  = (const float*)d_in[1];
    const int*   qe  = (const int*)d_in[2];
    const int*   te  = (const int*)d_in[3];
    const int*   ae  = (const int*)d_in[4];
    const int*   pe  = (const int*)d_in[5];
    const float* te_w1 = (const float*)d_in[6];  const float* te_b1 = (const float*)d_in[7];
    const float* te_w2 = (const float*)d_in[8];  const float* te_b2 = (const float*)d_in[9];
    const float* ee_w1 = (const float*)d_in[10]; const float* ee_b1 = (const float*)d_in[11];
    const float* ee_w2 = (const float*)d_in[12]; const float* ee_b2 = (const float*)d_in[13];
    const float* gw0 = (const float*)d_in[14];   const float* gb0 = (const float*)d_in[15];
    const float* gw1 = (const float*)d_in[16];   const float* gb1 = (const float*)d_in[17];
    const float* ta_w = (const float*)d_in[18];  const float* ta_b = (const float*)d_in[19];
    const float* ea_w = (const float*)d_in[20];  const float* ea_b = (const float*)d_in[21];
    const float* ow1 = (const float*)d_in[22];   const float* ob1 = (const float*)d_in[23];
    const float* ow2 = (const float*)d_in[24];   const float* ob2 = (const float*)d_in[25];

    const size_t NB = (size_t)NT * H;
    u16* T  = (u16*)d_ws;            // task emb (post-GNN)
    u16* Bf = T + NB;                // edge emb -> final edge emb
    u16* S  = Bf + NB;               // [fp8 queue sums] -> final task emb
    u16* F  = S + NB;                // GNN input (T+0.5S) -> e_new scratch
    u32* S8 = (u32*)S;               // fp8 queue sums (dead before task2 writes S)
    float* sumpad = (float*)(F + NB);
    int* off5   = (int*)(sumpad + 2 * H);              // 5*(NT+1)
    int* csr5   = off5 + 5 * (NT + 1);                 // 5*NE
    int* counts = csr5 + (size_t)5 * NE;               // CSR scratch (NOT aliased)
    int* starts = counts + (size_t)5 * NBLK * NBKT;
    int* bases  = starts + (size_t)5 * NBLK * NBKT;    // 5*(NBKT+1)
    // fp8 mirrors (NB bytes each)
    u32* M0 = (u32*)(((size_t)(bases + 5 * (NBKT + 1)) + 15) & ~(size_t)15);
    u32* M1 = M0 + NB / 4;
    u32* M2 = M1 + NB / 4;
    u32* M3 = M2 + NB / 4;
    u32* M4 = M3 + NB / 4;
    float* part = (float*)(M4 + NB / 4);               // 512*256 floats
    u16* warena = (u16*)(((size_t)(part + 512 * 256) + 15) & ~(size_t)15);
    u16* wt_te1_h = warena + 0;      u16* wt_te1_l = warena + 16384;
    u16* wt_te2_h = warena + 32768;  u16* wt_te2_l = warena + 98304;
    u16* wt_g0_h  = warena + 163840; u16* wt_g0_l  = warena + 229376;
    u16* wt_g1_h  = warena + 294912; u16* wt_g1_l  = warena + 360448;
    u16* wt_ee1_h = warena + 425984; u16* wt_ee1_l = warena + 442368;
    u16* wt_ee2_h = warena + 458752; u16* wt_ee2_l = warena + 524288;
    float* comb = (float*)(warena + 589824);           // 512 f32
    float* hidb = comb + 2 * H;                        // 256 f32

    const int MG = (NT + 63) / 64;                     // 782
    const int GB = (NT * 64) / 256;                    // 12500
    const int NPART = NBLK * 5;                        // 615
    const int NBUCK = NBKT * 5;                        // 1955

    const int *k0 = qe + NE, *k1 = te + NE, *k2 = ae,      *k3 = ae + NE, *k4 = pe + NE;
    const int *v0 = qe,      *v1 = te,      *v2 = ae + NE, *v3 = ae,      *v4 = pe;

    // ---- weight pack + CSR P1/P2 ----
    wt_pack<<<dim3(256, 6), 256, 0, stream>>>(te_w1, te_w2, gw0, gw1, ee_w1, ee_w2, warena);
    hist_kernel<<<dim3(NBLK, 5), 256, 0, stream>>>(k0, k1, k2, k3, k4, counts);
    scan_buckets<<<5, 256, 0, stream>>>(counts, starts, bases);

    // ---- combo 1: partition ∥ task encoder (-> T, M0) ----
    part_enc<<<NPART + MG, 256, 0, stream>>>(
        k0, k1, k2, k3, k4, v0, v1, v2, v3, v4, starts, csr5,
        tf, wt_te1_h, wt_te1_l, te_b1, wt_te2_h, wt_te2_l, te_b2, T, M0, NT, NPART);

    // ---- combo 2: bucket_csr ∥ edge encoder (-> Bf, M2) ----
    buck_enc<<<NBUCK + MG, 256, 0, stream>>>(
        bases, csr5, off5,
        ef, wt_ee1_h, wt_ee1_l, ee_b1, wt_ee2_h, wt_ee2_l, ee_b2, Bf, M2, NT, NBUCK);

    #define LOFF(l) (off5 + (l) * (NT + 1))
    #define LCSR(l) (csr5 + (size_t)(l) * NE)

    // ---- queue conv: S8 = fp8(segsum(M0[qs] by qt)); F = T + 0.5*sum ----
    gather_q_f8<<<GB, 256, 0, stream>>>(M0, LCSR(0), LOFF(0), T, S8, F, 0.5f, NT);

    // ---- GNN (fused 2 layers): X=F, L1 epilogue +0.5*S8 -> T (+ M1) ----
    fused_mlp<256><<<MG, 256, 0, stream>>>(
        F, S8, wt_g0_h, wt_g0_l, gb0, wt_g1_h, wt_g1_l, gb1, T, M1, NT, 0.5f);

    // ---- fused type + affinity-t (interleaved): S = final task emb, M3 = fp8 ----
    gather_task2<<<GB, 256, 0, stream>>>(
        M1, LCSR(1), LOFF(1), M2, LCSR(2), LOFF(2), T, S, M3, NT);

    // ---- affinity-e: F = Bf + 0.3*mean(M3[asrc] by atgt) (+ M4) ----
    gather_mean_f8<<<GB, 256, 0, stream>>>(
        M3, LCSR(3), LOFF(3), Bf, F, M4, 0.3f, NT);

    // ---- topology: Bf = F + 0.3*mean(M4[ps] by pt) ----
    gather_mean_f8<<<GB, 256, 0, stream>>>(
        M4, LCSR(4), LOFF(4), F, Bf, nullptr, 0.3f, NT);

    // ---- aggregation + head (task = S, edge = Bf), parallel head ----
    colsum_slots<<<512, 256, 0, stream>>>(S, Bf, part, NT);
    head_comb<<<16, 256, 0, stream>>>(part, 1.f / NT, 1.f / NEDGE,
                                      ta_w, ta_b, ea_w, ea_b, comb);
    head_hid<<<8, 256, 0, stream>>>(comb, ow1, ob1, hidb);
    head_out<<<8, 256, 0, stream>>>(hidb, ow2, ob2, (float*)d_out);
}

// Round 18
// 403.310 us; speedup vs baseline: 1.0633x; 1.0633x over previous
//
#include <hip/hip_runtime.h>

#define H 256
#define NT 50000      // num task nodes
#define NEDGE 50000   // num edge nodes
#define NE 500000     // edges per edge-type

#define NBKT 391      // coarse buckets = ceil(50000/128), key>>7
#define NBLK 123      // edge chunks   = ceil(500000/4096)
#define CHUNK 4096
#define CAP 2816      // max bucket size guard

typedef __attribute__((ext_vector_type(8))) short short8_t;  // 8 bf16 (4 VGPR)
typedef __attribute__((ext_vector_type(4))) float f32x4;
typedef unsigned short u16;
typedef unsigned int u32;

__device__ __forceinline__ float b2f(u16 v) { return __uint_as_float((u32)v << 16); }
__device__ __forceinline__ u16 f2b(float f) {
    u32 u = __float_as_uint(f);
    u += 0x7FFFu + ((u >> 16) & 1u);
    return (u16)(u >> 16);
}

// ---- fp8 e4m3 (OCP) pack/unpack, HW cvt when available ----
__device__ __forceinline__ u32 f2fp8_1(float f) {
    u32 u = __float_as_uint(f);
    u32 s = (u >> 24) & 0x80u;
    float af = fabsf(f);
    if (af >= 448.f) return s | 0x7Eu;
    if (af < 0.015625f) {
        int m = (int)rintf(af * 512.0f);
        return s | (u32)m;
    }
    u32 au = __float_as_uint(af);
    u32 r = au + 0x7FFFFu + ((au >> 20) & 1u);
    int e = (int)(r >> 23) - 127;
    return s | (u32)(((e + 7) << 3) | ((r >> 20) & 7u));
}
__device__ __forceinline__ float fp82f_1(u32 b) {
    u32 s = (b & 0x80u) << 24;
    u32 em = b & 0x7Fu;
    float v;
    if (em >= 8) v = __uint_as_float((((em >> 3) + 120u) << 23) | ((em & 7u) << 20));
    else v = (float)em * 0.001953125f;
    return __uint_as_float(__float_as_uint(v) | s);
}
__device__ __forceinline__ u32 pk4_fp8(float a, float b, float c, float d) {
#if __has_builtin(__builtin_amdgcn_cvt_pk_fp8_f32)
    u32 r = 0;
    r = (u32)__builtin_amdgcn_cvt_pk_fp8_f32(a, b, (int)r, false);
    r = (u32)__builtin_amdgcn_cvt_pk_fp8_f32(c, d, (int)r, true);
    return r;
#else
    return f2fp8_1(a) | (f2fp8_1(b) << 8) | (f2fp8_1(c) << 16) | (f2fp8_1(d) << 24);
#endif
}
__device__ __forceinline__ float4 unpk4_fp8(u32 v) {
#if __has_builtin(__builtin_amdgcn_cvt_pk_f32_fp8)
    auto lo = __builtin_amdgcn_cvt_pk_f32_fp8(v, false);
    auto hi = __builtin_amdgcn_cvt_pk_f32_fp8(v, true);
    return make_float4(lo[0], lo[1], hi[0], hi[1]);
#else
    return make_float4(fp82f_1(v & 255u), fp82f_1((v >> 8) & 255u),
                       fp82f_1((v >> 16) & 255u), fp82f_1(v >> 24));
#endif
}

__device__ __forceinline__ const int* pick_list(
    int l, const int* a, const int* b, const int* c, const int* d, const int* e)
{ return (l == 0) ? a : (l == 1) ? b : (l == 2) ? c : (l == 3) ? d : e; }

// ---------------- encoder body (K1=64, fp32 input) — shared by combo kernels ----------------
__device__ __forceinline__ void enc_body(
    char* arena, int bid, const float* __restrict__ X,
    const u16* __restrict__ W1h, const u16* __restrict__ W1l, const float* __restrict__ b1,
    const u16* __restrict__ W2h, const u16* __restrict__ W2l, const float* __restrict__ b2,
    u16* __restrict__ out, u32* __restrict__ f8, int N)
{
    const int m0 = bid * 64;

    for (int i = threadIdx.x; i < 64 * 8; i += 256) {
        int r = i >> 3, c8 = i & 7;
        int gr = m0 + r; if (gr >= N) gr = N - 1;
        const float* xf = X + (size_t)gr * 64 + c8 * 8;
        float4 a = *(const float4*)xf;
        float4 b = *(const float4*)(xf + 4);
        uint4 v;
        v.x = (u32)f2b(a.x) | ((u32)f2b(a.y) << 16);
        v.y = (u32)f2b(a.z) | ((u32)f2b(a.w) << 16);
        v.z = (u32)f2b(b.x) | ((u32)f2b(b.y) << 16);
        v.w = (u32)f2b(b.z) | ((u32)f2b(b.w) << 16);
        u32 byte = (u32)(r * 128 + c8 * 16) ^ (u32)((r & 7) << 4);
        *(uint4*)(arena + byte) = v;
    }
    __syncthreads();

    const int wv = threadIdx.x >> 6, l = threadIdx.x & 63;
    const int li = l & 15, lk = l >> 4;

    f32x4 acc[4][4];
    #pragma unroll
    for (int i = 0; i < 4; i++)
        #pragma unroll
        for (int j = 0; j < 4; j++)
            acc[i][j] = (f32x4){0.f, 0.f, 0.f, 0.f};

    // layer 1 (K=64, 2 k-steps, pipelined)
    {
        short8_t whc[4], wlc[4];
        #pragma unroll
        for (int ni = 0; ni < 4; ni++) {
            const size_t wi = (size_t)((wv * 4 + ni) * 2) * 64 + l;
            whc[ni] = ((const short8_t*)W1h)[wi];
            wlc[ni] = ((const short8_t*)W1l)[wi];
        }
        #pragma unroll
        for (int ks = 0; ks < 2; ks++) {
            short8_t whn[4], wln[4];
            if (ks + 1 < 2) {
                #pragma unroll
                for (int ni = 0; ni < 4; ni++) {
                    const size_t wi = (size_t)((wv * 4 + ni) * 2 + ks + 1) * 64 + l;
                    whn[ni] = ((const short8_t*)W1h)[wi];
                    wln[ni] = ((const short8_t*)W1l)[wi];
                }
            }
            short8_t xb[4];
            #pragma unroll
            for (int mi = 0; mi < 4; mi++) {
                int m = mi * 16 + li;
                u32 byte = (u32)(m * 128 + (ks * 32 + lk * 8) * 2) ^ (u32)((m & 7) << 4);
                xb[mi] = *(const short8_t*)(arena + byte);
            }
            __builtin_amdgcn_s_setprio(1);
            #pragma unroll
            for (int ni = 0; ni < 4; ni++)
                #pragma unroll
                for (int mi = 0; mi < 4; mi++) {
                    acc[mi][ni] = __builtin_amdgcn_mfma_f32_16x16x32_bf16(wlc[ni], xb[mi], acc[mi][ni], 0, 0, 0);
                    acc[mi][ni] = __builtin_amdgcn_mfma_f32_16x16x32_bf16(whc[ni], xb[mi], acc[mi][ni], 0, 0, 0);
                }
            __builtin_amdgcn_s_setprio(0);
            if (ks + 1 < 2) {
                #pragma unroll
                for (int ni = 0; ni < 4; ni++) { whc[ni] = whn[ni]; wlc[ni] = wln[ni]; }
            }
        }
    }

    __syncthreads();

    #pragma unroll
    for (int ni = 0; ni < 4; ni++) {
        int c = wv * 64 + ni * 16 + lk * 4;
        float4 b4 = *(const float4*)(b1 + c);
        #pragma unroll
        for (int mi = 0; mi < 4; mi++) {
            int m = mi * 16 + li;
            float o0 = fmaxf(acc[mi][ni][0] + b4.x, 0.f);
            float o1 = fmaxf(acc[mi][ni][1] + b4.y, 0.f);
            float o2 = fmaxf(acc[mi][ni][2] + b4.z, 0.f);
            float o3 = fmaxf(acc[mi][ni][3] + b4.w, 0.f);
            u32 w0 = (u32)f2b(o0) | ((u32)f2b(o1) << 16);
            u32 w1 = (u32)f2b(o2) | ((u32)f2b(o3) << 16);
            u32 byte = (u32)(m * 512 + c * 2) ^ (u32)((m & 7) << 4);
            *(uint2*)(arena + byte) = make_uint2(w0, w1);
        }
    }
    __syncthreads();

    #pragma unroll
    for (int i = 0; i < 4; i++)
        #pragma unroll
        for (int j = 0; j < 4; j++)
            acc[i][j] = (f32x4){0.f, 0.f, 0.f, 0.f};

    // layer 2 (K=256, pipelined)
    {
        short8_t whc[4], wlc[4];
        #pragma unroll
        for (int ni = 0; ni < 4; ni++) {
            const size_t wi = (size_t)((wv * 4 + ni) * 8) * 64 + l;
            whc[ni] = ((const short8_t*)W2h)[wi];
            wlc[ni] = ((const short8_t*)W2l)[wi];
        }
        #pragma unroll
        for (int ks = 0; ks < 8; ks++) {
            short8_t whn[4], wln[4];
            if (ks + 1 < 8) {
                #pragma unroll
                for (int ni = 0; ni < 4; ni++) {
                    const size_t wi = (size_t)((wv * 4 + ni) * 8 + ks + 1) * 64 + l;
                    whn[ni] = ((const short8_t*)W2h)[wi];
                    wln[ni] = ((const short8_t*)W2l)[wi];
                }
            }
            short8_t xb[4];
            #pragma unroll
            for (int mi = 0; mi < 4; mi++) {
                int m = mi * 16 + li;
                u32 byte = (u32)(m * 512 + (ks * 32 + lk * 8) * 2) ^ (u32)((m & 7) << 4);
                xb[mi] = *(const short8_t*)(arena + byte);
            }
            __builtin_amdgcn_s_setprio(1);
            #pragma unroll
            for (int ni = 0; ni < 4; ni++)
                #pragma unroll
                for (int mi = 0; mi < 4; mi++) {
                    acc[mi][ni] = __builtin_amdgcn_mfma_f32_16x16x32_bf16(wlc[ni], xb[mi], acc[mi][ni], 0, 0, 0);
                    acc[mi][ni] = __builtin_amdgcn_mfma_f32_16x16x32_bf16(whc[ni], xb[mi], acc[mi][ni], 0, 0, 0);
                }
            __builtin_amdgcn_s_setprio(0);
            if (ks + 1 < 8) {
                #pragma unroll
                for (int ni = 0; ni < 4; ni++) { whc[ni] = whn[ni]; wlc[ni] = wln[ni]; }
            }
        }
    }

    __syncthreads();
    #pragma unroll
    for (int ni = 0; ni < 4; ni++) {
        int c = wv * 64 + ni * 16 + lk * 4;
        float4 b4 = *(const float4*)(b2 + c);
        #pragma unroll
        for (int mi = 0; mi < 4; mi++) {
            int m = mi * 16 + li;
            float o0 = fmaxf(acc[mi][ni][0] + b4.x, 0.f);
            float o1 = fmaxf(acc[mi][ni][1] + b4.y, 0.f);
            float o2 = fmaxf(acc[mi][ni][2] + b4.z, 0.f);
            float o3 = fmaxf(acc[mi][ni][3] + b4.w, 0.f);
            u32 w0 = (u32)f2b(o0) | ((u32)f2b(o1) << 16);
            u32 w1 = (u32)f2b(o2) | ((u32)f2b(o3) << 16);
            u32 byte = (u32)(m * 512 + c * 2) ^ (u32)((m & 7) << 4);
            *(uint2*)(arena + byte) = make_uint2(w0, w1);
        }
    }
    __syncthreads();
    for (int i = threadIdx.x; i < 64 * 32; i += 256) {
        int r = i >> 5, c8 = i & 31;
        int m = m0 + r;
        if (m < N) {
            u32 byte = (u32)(r * 512 + c8 * 16) ^ (u32)((r & 7) << 4);
            uint4 v = *(const uint4*)(arena + byte);
            *(uint4*)(out + (size_t)m * H + c8 * 8) = v;
            u32 p0 = pk4_fp8(b2f((u16)(v.x & 0xFFFF)), b2f((u16)(v.x >> 16)),
                             b2f((u16)(v.y & 0xFFFF)), b2f((u16)(v.y >> 16)));
            u32 p1 = pk4_fp8(b2f((u16)(v.z & 0xFFFF)), b2f((u16)(v.z >> 16)),
                             b2f((u16)(v.w & 0xFFFF)), b2f((u16)(v.w >> 16)));
            *(uint2*)(f8 + (size_t)m * 64 + c8 * 2) = make_uint2(p0, p1);
        }
    }
}

// ---------------- combo: partition ∥ task encoder ----------------
__global__ __launch_bounds__(256) void part_enc(
    const int* __restrict__ k0, const int* __restrict__ k1, const int* __restrict__ k2,
    const int* __restrict__ k3, const int* __restrict__ k4,
    const int* __restrict__ v0, const int* __restrict__ v1, const int* __restrict__ v2,
    const int* __restrict__ v3, const int* __restrict__ v4,
    const int* __restrict__ starts, int* __restrict__ csr,
    const float* __restrict__ X,
    const u16* __restrict__ W1h, const u16* __restrict__ W1l, const float* __restrict__ b1,
    const u16* __restrict__ W2h, const u16* __restrict__ W2l, const float* __restrict__ b2,
    u16* __restrict__ out, u32* __restrict__ f8, int N, int nCSR)
{
    __shared__ char arena[32768];
    if ((int)blockIdx.x >= nCSR) {
        enc_body(arena, blockIdx.x - nCSR, X, W1h, W1l, b1, W2h, W2l, b2, out, f8, N);
        return;
    }
    u32* ent = (u32*)arena;
    u16* ebk = (u16*)(arena + 16384);
    int* cnt  = (int*)(arena + 24576);
    int* loff = cnt + NBKT;
    int* cur  = loff + NBKT;
    int* gst  = cur + NBKT;
    int* buf  = (int*)(arena + 24576 + 4 * 4 * NBKT);
    int p = blockIdx.x;
    int l = p / NBLK, blk = p % NBLK;
    int t = threadIdx.x;
    const int* k = pick_list(l, k0, k1, k2, k3, k4);
    const int* v = pick_list(l, v0, v1, v2, v3, v4);
    const int* st = starts + ((size_t)l * NBLK + blk) * NBKT;
    for (int i = t; i < NBKT; i += 256) { cnt[i] = 0; gst[i] = st[i]; }
    __syncthreads();
    int e0 = blk * CHUNK;
    u32 ep[16]; int eb[16];
    #pragma unroll
    for (int j = 0; j < 16; j++) {
        int e = e0 + j * 256 + t;
        if (e < NE) {
            int key = k[e];
            eb[j] = key >> 7;
            ep[j] = ((u32)(key & 127) << 16) | (u32)v[e];
            atomicAdd(&cnt[eb[j]], 1);
        } else eb[j] = -1;
    }
    __syncthreads();
    int b0 = t * 2;
    int c0 = (b0 < NBKT) ? cnt[b0] : 0;
    int c1 = (b0 + 1 < NBKT) ? cnt[b0 + 1] : 0;
    int s = c0 + c1;
    buf[t] = s; __syncthreads();
    for (int stp = 1; stp < 256; stp <<= 1) {
        int x = (t >= stp) ? buf[t - stp] : 0; __syncthreads();
        buf[t] += x; __syncthreads();
    }
    int run = buf[t] - s;
    if (b0 < NBKT)     { loff[b0] = run;          cur[b0] = run; }
    if (b0 + 1 < NBKT) { loff[b0 + 1] = run + c0; cur[b0 + 1] = run + c0; }
    __syncthreads();
    #pragma unroll
    for (int j = 0; j < 16; j++) {
        if (eb[j] >= 0) {
            int q = atomicAdd(&cur[eb[j]], 1);
            ent[q] = ep[j]; ebk[q] = (u16)eb[j];
        }
    }
    __syncthreads();
    int nv = min(CHUNK, NE - e0);
    int* c = csr + (size_t)l * NE;
    for (int i = t; i < nv; i += 256) {
        int b = ebk[i];
        c[gst[b] + (i - loff[b])] = (int)ent[i];
    }
}

// ---------------- combo: bucket_csr ∥ edge encoder ----------------
__global__ __launch_bounds__(256) void buck_enc(
    const int* __restrict__ bases, int* __restrict__ csr, int* __restrict__ off,
    const float* __restrict__ X,
    const u16* __restrict__ W1h, const u16* __restrict__ W1l, const float* __restrict__ b1,
    const u16* __restrict__ W2h, const u16* __restrict__ W2l, const float* __restrict__ b2,
    u16* __restrict__ out, u32* __restrict__ f8, int N, int nCSR)
{
    __shared__ char arena[32768];
    if ((int)blockIdx.x >= nCSR) {
        enc_body(arena, blockIdx.x - nCSR, X, W1h, W1l, b1, W2h, W2l, b2, out, f8, N);
        return;
    }
    int* seg  = (int*)arena;
    int* hist = (int*)(arena + 11264);
    int* scn  = hist + 128;
    int p = blockIdx.x;
    int l = p / NBKT, b = p % NBKT;
    int t = threadIdx.x;
    int base = bases[l * (NBKT + 1) + b];
    int end  = bases[l * (NBKT + 1) + b + 1];
    int sz = end - base; if (sz > CAP) sz = CAP;
    int* c = csr + (size_t)l * NE;
    for (int i = t; i < sz; i += 256) seg[i] = c[base + i];
    if (t < 128) hist[t] = 0;
    __syncthreads();
    for (int i = t; i < sz; i += 256) atomicAdd(&hist[seg[i] >> 16], 1);
    __syncthreads();
    if (t < 128) scn[t] = hist[t];
    __syncthreads();
    for (int st = 1; st < 128; st <<= 1) {
        int v = 0;
        if (t < 128 && t >= st) v = scn[t - st];
        __syncthreads();
        if (t < 128) scn[t] += v;
        __syncthreads();
    }
    if (t < 128) {
        int key = b * 128 + t;
        int excl = scn[t] - hist[t];
        if (key < NT) off[l * (NT + 1) + key] = base + excl;
        hist[t] = excl;
    }
    if (b == 0 && t == 128) off[l * (NT + 1) + NT] = NE;
    __syncthreads();
    for (int i = t; i < sz; i += 256) {
        int u = seg[i];
        int q = atomicAdd(&hist[u >> 16], 1);
        c[base + q] = u & 0xFFFF;
    }
}

// ---------------- GNN fused 2-layer MLP (K1=256, fp8 queue fuse) ----------------
template<int K1>
__global__ __launch_bounds__(256) void fused_mlp(
    const u16* __restrict__ X, const u32* __restrict__ Q8,
    const u16* __restrict__ W1h, const u16* __restrict__ W1l, const float* __restrict__ b1,
    const u16* __restrict__ W2h, const u16* __restrict__ W2l, const float* __restrict__ b2,
    u16* __restrict__ out, u32* __restrict__ f8,
    int N, float s2)
{
    __shared__ u16 lds[64 * 256];
    const int m0 = blockIdx.x * 64;

    constexpr int RCH = K1 / 8;
    for (int i = threadIdx.x; i < 64 * RCH; i += 256) {
        int r = i / RCH, c8 = i % RCH;
        int gr = m0 + r; if (gr >= N) gr = N - 1;
        uint4 v = *(const uint4*)(X + (size_t)gr * K1 + c8 * 8);
        u32 byte = (u32)(r * (K1 * 2) + c8 * 16) ^ (u32)((r & 7) << 4);
        *(uint4*)((char*)lds + byte) = v;
    }
    __syncthreads();

    const int wv = threadIdx.x >> 6, l = threadIdx.x & 63;
    const int li = l & 15, lk = l >> 4;

    f32x4 acc[4][4];
    #pragma unroll
    for (int i = 0; i < 4; i++)
        #pragma unroll
        for (int j = 0; j < 4; j++)
            acc[i][j] = (f32x4){0.f, 0.f, 0.f, 0.f};

    {
        constexpr int KS = K1 / 32;
        short8_t whc[4], wlc[4];
        #pragma unroll
        for (int ni = 0; ni < 4; ni++) {
            const size_t wi = (size_t)((wv * 4 + ni) * KS) * 64 + l;
            whc[ni] = ((const short8_t*)W1h)[wi];
            wlc[ni] = ((const short8_t*)W1l)[wi];
        }
        #pragma unroll
        for (int ks = 0; ks < KS; ks++) {
            short8_t whn[4], wln[4];
            if (ks + 1 < KS) {
                #pragma unroll
                for (int ni = 0; ni < 4; ni++) {
                    const size_t wi = (size_t)((wv * 4 + ni) * KS + ks + 1) * 64 + l;
                    whn[ni] = ((const short8_t*)W1h)[wi];
                    wln[ni] = ((const short8_t*)W1l)[wi];
                }
            }
            short8_t xb[4];
            #pragma unroll
            for (int mi = 0; mi < 4; mi++) {
                int m = mi * 16 + li;
                u32 byte = (u32)(m * (K1 * 2) + (ks * 32 + lk * 8) * 2) ^ (u32)((m & 7) << 4);
                xb[mi] = *(const short8_t*)((const char*)lds + byte);
            }
            __builtin_amdgcn_s_setprio(1);
            #pragma unroll
            for (int ni = 0; ni < 4; ni++)
                #pragma unroll
                for (int mi = 0; mi < 4; mi++) {
                    acc[mi][ni] = __builtin_amdgcn_mfma_f32_16x16x32_bf16(wlc[ni], xb[mi], acc[mi][ni], 0, 0, 0);
                    acc[mi][ni] = __builtin_amdgcn_mfma_f32_16x16x32_bf16(whc[ni], xb[mi], acc[mi][ni], 0, 0, 0);
                }
            __builtin_amdgcn_s_setprio(0);
            if (ks + 1 < KS) {
                #pragma unroll
                for (int ni = 0; ni < 4; ni++) { whc[ni] = whn[ni]; wlc[ni] = wln[ni]; }
            }
        }
    }

    __syncthreads();

    #pragma unroll
    for (int ni = 0; ni < 4; ni++) {
        int c = wv * 64 + ni * 16 + lk * 4;
        float4 b4 = *(const float4*)(b1 + c);
        #pragma unroll
        for (int mi = 0; mi < 4; mi++) {
            int m = mi * 16 + li;
            float o0 = fmaxf(acc[mi][ni][0] + b4.x, 0.f);
            float o1 = fmaxf(acc[mi][ni][1] + b4.y, 0.f);
            float o2 = fmaxf(acc[mi][ni][2] + b4.z, 0.f);
            float o3 = fmaxf(acc[mi][ni][3] + b4.w, 0.f);
            int gm = m0 + m; if (gm >= N) gm = N - 1;
            float4 qf = unpk4_fp8(Q8[(size_t)gm * 64 + (c >> 2)]);
            o0 = fmaf(s2, qf.x, o0);
            o1 = fmaf(s2, qf.y, o1);
            o2 = fmaf(s2, qf.z, o2);
            o3 = fmaf(s2, qf.w, o3);
            u32 w0 = (u32)f2b(o0) | ((u32)f2b(o1) << 16);
            u32 w1 = (u32)f2b(o2) | ((u32)f2b(o3) << 16);
            u32 byte = (u32)(m * 512 + c * 2) ^ (u32)((m & 7) << 4);
            *(uint2*)((char*)lds + byte) = make_uint2(w0, w1);
        }
    }
    __syncthreads();

    #pragma unroll
    for (int i = 0; i < 4; i++)
        #pragma unroll
        for (int j = 0; j < 4; j++)
            acc[i][j] = (f32x4){0.f, 0.f, 0.f, 0.f};

    {
        short8_t whc[4], wlc[4];
        #pragma unroll
        for (int ni = 0; ni < 4; ni++) {
            const size_t wi = (size_t)((wv * 4 + ni) * 8) * 64 + l;
            whc[ni] = ((const short8_t*)W2h)[wi];
            wlc[ni] = ((const short8_t*)W2l)[wi];
        }
        #pragma unroll
        for (int ks = 0; ks < 8; ks++) {
            short8_t whn[4], wln[4];
            if (ks + 1 < 8) {
                #pragma unroll
                for (int ni = 0; ni < 4; ni++) {
                    const size_t wi = (size_t)((wv * 4 + ni) * 8 + ks + 1) * 64 + l;
                    whn[ni] = ((const short8_t*)W2h)[wi];
                    wln[ni] = ((const short8_t*)W2l)[wi];
                }
            }
            short8_t xb[4];
            #pragma unroll
            for (int mi = 0; mi < 4; mi++) {
                int m = mi * 16 + li;
                u32 byte = (u32)(m * 512 + (ks * 32 + lk * 8) * 2) ^ (u32)((m & 7) << 4);
                xb[mi] = *(const short8_t*)((const char*)lds + byte);
            }
            __builtin_amdgcn_s_setprio(1);
            #pragma unroll
            for (int ni = 0; ni < 4; ni++)
                #pragma unroll
                for (int mi = 0; mi < 4; mi++) {
                    acc[mi][ni] = __builtin_amdgcn_mfma_f32_16x16x32_bf16(wlc[ni], xb[mi], acc[mi][ni], 0, 0, 0);
                    acc[mi][ni] = __builtin_amdgcn_mfma_f32_16x16x32_bf16(whc[ni], xb[mi], acc[mi][ni], 0, 0, 0);
                }
            __builtin_amdgcn_s_setprio(0);
            if (ks + 1 < 8) {
                #pragma unroll
                for (int ni = 0; ni < 4; ni++) { whc[ni] = whn[ni]; wlc[ni] = wln[ni]; }
            }
        }
    }

    __syncthreads();
    #pragma unroll
    for (int ni = 0; ni < 4; ni++) {
        int c = wv * 64 + ni * 16 + lk * 4;
        float4 b4 = *(const float4*)(b2 + c);
        #pragma unroll
        for (int mi = 0; mi < 4; mi++) {
            int m = mi * 16 + li;
            float o0 = fmaxf(acc[mi][ni][0] + b4.x, 0.f);
            float o1 = fmaxf(acc[mi][ni][1] + b4.y, 0.f);
            float o2 = fmaxf(acc[mi][ni][2] + b4.z, 0.f);
            float o3 = fmaxf(acc[mi][ni][3] + b4.w, 0.f);
            u32 w0 = (u32)f2b(o0) | ((u32)f2b(o1) << 16);
            u32 w1 = (u32)f2b(o2) | ((u32)f2b(o3) << 16);
            u32 byte = (u32)(m * 512 + c * 2) ^ (u32)((m & 7) << 4);
            *(uint2*)((char*)lds + byte) = make_uint2(w0, w1);
        }
    }
    __syncthreads();
    for (int i = threadIdx.x; i < 64 * 32; i += 256) {
        int r = i >> 5, c8 = i & 31;
        int m = m0 + r;
        if (m < N) {
            u32 byte = (u32)(r * 512 + c8 * 16) ^ (u32)((r & 7) << 4);
            uint4 v = *(const uint4*)((const char*)lds + byte);
            *(uint4*)(out + (size_t)m * H + c8 * 8) = v;
            u32 p0 = pk4_fp8(b2f((u16)(v.x & 0xFFFF)), b2f((u16)(v.x >> 16)),
                             b2f((u16)(v.y & 0xFFFF)), b2f((u16)(v.y >> 16)));
            u32 p1 = pk4_fp8(b2f((u16)(v.z & 0xFFFF)), b2f((u16)(v.z >> 16)),
                             b2f((u16)(v.w & 0xFFFF)), b2f((u16)(v.w >> 16)));
            *(uint2*)(f8 + (size_t)m * 64 + c8 * 2) = make_uint2(p0, p1);
        }
    }
}

// W [K][256] fp32 -> packed fragment-order hi/lo bf16 mirrors
__global__ __launch_bounds__(256) void wt_pack(
    const float* __restrict__ s0, const float* __restrict__ s1,
    const float* __restrict__ s2, const float* __restrict__ s3,
    const float* __restrict__ s4, const float* __restrict__ s5,
    u16* __restrict__ arena)
{
    const int li = blockIdx.y;
    const int K = (li == 0 || li == 4) ? 64 : 256;
    const int offs[6] = {0, 32768, 163840, 294912, 425984, 458752};
    int n = K * 256;
    int i = blockIdx.x * 256 + threadIdx.x;
    if (i >= n) return;
    const float* W = (li == 0) ? s0 : (li == 1) ? s1 : (li == 2) ? s2
                   : (li == 3) ? s3 : (li == 4) ? s4 : s5;
    u16* hi = arena + offs[li];
    u16* lo = hi + n;
    int k = i >> 8, c = i & 255;
    float u = W[i];
    u32 b = __float_as_uint(u);
    float r = u - __uint_as_float(b & 0xFFFF0000u);
    int lane = ((k >> 3) & 3) * 16 + (c & 15);
    size_t idx = ((size_t)((c >> 4) * (K >> 5) + (k >> 5)) * 64 + lane) * 8 + (k & 7);
    hi[idx] = (u16)(b >> 16);
    lo[idx] = f2b(r);
}

// ---------------- CSR build P1/P2 ----------------
__global__ __launch_bounds__(256) void hist_kernel(
    const int* __restrict__ k0, const int* __restrict__ k1, const int* __restrict__ k2,
    const int* __restrict__ k3, const int* __restrict__ k4, int* __restrict__ counts)
{
    __shared__ int h[NBKT];
    int l = blockIdx.y;
    const int* k = pick_list(l, k0, k1, k2, k3, k4);
    for (int i = threadIdx.x; i < NBKT; i += 256) h[i] = 0;
    __syncthreads();
    int e0 = blockIdx.x * CHUNK;
    for (int i = threadIdx.x; i < CHUNK; i += 256) {
        int e = e0 + i;
        if (e < NE) atomicAdd(&h[k[e] >> 7], 1);
    }
    __syncthreads();
    int* out = counts + ((size_t)l * NBLK + blockIdx.x) * NBKT;
    for (int i = threadIdx.x; i < NBKT; i += 256) out[i] = h[i];
}

__global__ __launch_bounds__(256) void scan_buckets(
    const int* __restrict__ counts, int* __restrict__ starts, int* __restrict__ bases)
{
    __shared__ int buf[256];
    int l = blockIdx.x, t = threadIdx.x;
    const int* cl = counts + (size_t)l * NBLK * NBKT;
    int* sl = starts + (size_t)l * NBLK * NBKT;
    int b0 = t * 2;
    int totloc[2];
    int s = 0;
    #pragma unroll
    for (int j = 0; j < 2; j++) {
        int b = b0 + j, v = 0;
        if (b < NBKT) for (int k = 0; k < NBLK; k++) v += cl[k * NBKT + b];
        totloc[j] = v; s += v;
    }
    buf[t] = s; __syncthreads();
    for (int st = 1; st < 256; st <<= 1) {
        int v = (t >= st) ? buf[t - st] : 0; __syncthreads();
        buf[t] += v; __syncthreads();
    }
    int run = buf[t] - s;
    #pragma unroll
    for (int j = 0; j < 2; j++) {
        int b = b0 + j;
        if (b < NBKT) {
            bases[l * (NBKT + 1) + b] = run;
            int p = run;
            for (int k = 0; k < NBLK; k++) { sl[k * NBKT + b] = p; p += cl[k * NBKT + b]; }
            run += totloc[j];
        }
    }
    if (t == 255) bases[l * (NBKT + 1) + NBKT] = NE;
}

// ---------------- gathers (fp8 src, 8-deep pipeline) ----------------
// queue conv: S8 = fp8(segsum); F = T + s2*segsum (bf16)
__global__ __launch_bounds__(256) void gather_q_f8(
    const u32* __restrict__ src, const int* __restrict__ csr,
    const int* __restrict__ off, const u16* __restrict__ baseT,
    u32* __restrict__ S8out, u16* __restrict__ fuseOut, float s2, int N)
{
    int r = (blockIdx.x * 256 + threadIdx.x) >> 6;
    int lane = threadIdx.x & 63;
    if (r >= N) return;
    int o0 = off[r];
    int d  = off[r + 1] - o0;
    float4 acc = {0.f, 0.f, 0.f, 0.f};
    int j = 0;
    for (; j + 8 <= d; j += 8) {
        u32 w[8];
        #pragma unroll
        for (int q = 0; q < 8; q++)
            w[q] = src[(size_t)csr[o0 + j + q] * 64 + lane];
        #pragma unroll
        for (int q = 0; q < 8; q++) {
            float4 f = unpk4_fp8(w[q]);
            acc.x += f.x; acc.y += f.y; acc.z += f.z; acc.w += f.w;
        }
    }
    for (; j < d; j++) {
        float4 f = unpk4_fp8(src[(size_t)csr[o0 + j] * 64 + lane]);
        acc.x += f.x; acc.y += f.y; acc.z += f.z; acc.w += f.w;
    }
    S8out[(size_t)r * 64 + lane] = pk4_fp8(acc.x, acc.y, acc.z, acc.w);
    ushort4 b = ((const ushort4*)(baseT + (size_t)r * H))[lane];
    ushort4 pk;
    pk.x = f2b(fmaf(s2, acc.x, b2f(b.x)));
    pk.y = f2b(fmaf(s2, acc.y, b2f(b.y)));
    pk.z = f2b(fmaf(s2, acc.z, b2f(b.z)));
    pk.w = f2b(fmaf(s2, acc.w, b2f(b.w)));
    ((ushort4*)(fuseOut + (size_t)r * H))[lane] = pk;
}

// fused type-conv + affinity-t: two clean serial 8-deep pipelines (r16-proven)
__global__ __launch_bounds__(256) void gather_task2(
    const u32* __restrict__ M1s, const int* __restrict__ csr1, const int* __restrict__ off1,
    const u32* __restrict__ M2s, const int* __restrict__ csr2, const int* __restrict__ off2,
    const u16* __restrict__ T, u16* __restrict__ Sout, u32* __restrict__ M3out, int N)
{
    int r = (blockIdx.x * 256 + threadIdx.x) >> 6;
    int lane = threadIdx.x & 63;
    if (r >= N) return;

    float4 a1 = {0.f, 0.f, 0.f, 0.f};
    {
        int o0 = off1[r], d = off1[r + 1] - o0;
        int j = 0;
        for (; j + 8 <= d; j += 8) {
            u32 w[8];
            #pragma unroll
            for (int q = 0; q < 8; q++)
                w[q] = M1s[(size_t)csr1[o0 + j + q] * 64 + lane];
            #pragma unroll
            for (int q = 0; q < 8; q++) {
                float4 f = unpk4_fp8(w[q]);
                a1.x += f.x; a1.y += f.y; a1.z += f.z; a1.w += f.w;
            }
        }
        for (; j < d; j++) {
            float4 f = unpk4_fp8(M1s[(size_t)csr1[o0 + j] * 64 + lane]);
            a1.x += f.x; a1.y += f.y; a1.z += f.z; a1.w += f.w;
        }
        float s = 0.3f / (float)max(d, 1);
        a1.x *= s; a1.y *= s; a1.z *= s; a1.w *= s;
    }
    float4 a2 = {0.f, 0.f, 0.f, 0.f};
    {
        int o0 = off2[r], d = off2[r + 1] - o0;
        int j = 0;
        for (; j + 8 <= d; j += 8) {
            u32 w[8];
            #pragma unroll
            for (int q = 0; q < 8; q++)
                w[q] = M2s[(size_t)csr2[o0 + j + q] * 64 + lane];
            #pragma unroll
            for (int q = 0; q < 8; q++) {
                float4 f = unpk4_fp8(w[q]);
                a2.x += f.x; a2.y += f.y; a2.z += f.z; a2.w += f.w;
            }
        }
        for (; j < d; j++) {
            float4 f = unpk4_fp8(M2s[(size_t)csr2[o0 + j] * 64 + lane]);
            a2.x += f.x; a2.y += f.y; a2.z += f.z; a2.w += f.w;
        }
        float s = 0.3f / (float)max(d, 1);
        a2.x *= s; a2.y *= s; a2.z *= s; a2.w *= s;
    }
    ushort4 b = ((const ushort4*)(T + (size_t)r * H))[lane];
    float f0 = b2f(b.x) + a1.x, f1 = b2f(b.y) + a1.y;
    float f2 = b2f(b.z) + a1.z, f3 = b2f(b.w) + a1.w;
    M3out[(size_t)r * 64 + lane] = pk4_fp8(f0, f1, f2, f3);
    ushort4 pk;
    pk.x = f2b(f0 + a2.x); pk.y = f2b(f1 + a2.y);
    pk.z = f2b(f2 + a2.z); pk.w = f2b(f3 + a2.w);
    ((ushort4*)(Sout + (size_t)r * H))[lane] = pk;
}

__global__ __launch_bounds__(256) void gather_mean_f8(
    const u32* __restrict__ src, const int* __restrict__ csr, const int* __restrict__ off,
    const u16* __restrict__ base, u16* __restrict__ dst, u32* __restrict__ m8,
    float alpha, int N)
{
    int r = (blockIdx.x * 256 + threadIdx.x) >> 6;
    int lane = threadIdx.x & 63;
    if (r >= N) return;
    int o0 = off[r];
    int d  = off[r + 1] - o0;
    float4 acc = {0.f, 0.f, 0.f, 0.f};
    int j = 0;
    for (; j + 8 <= d; j += 8) {
        u32 w[8];
        #pragma unroll
        for (int q = 0; q < 8; q++)
            w[q] = src[(size_t)csr[o0 + j + q] * 64 + lane];
        #pragma unroll
        for (int q = 0; q < 8; q++) {
            float4 f = unpk4_fp8(w[q]);
            acc.x += f.x; acc.y += f.y; acc.z += f.z; acc.w += f.w;
        }
    }
    for (; j < d; j++) {
        float4 f = unpk4_fp8(src[(size_t)csr[o0 + j] * 64 + lane]);
        acc.x += f.x; acc.y += f.y; acc.z += f.z; acc.w += f.w;
    }
    float s = alpha / (float)max(d, 1);
    ushort4 b = ((const ushort4*)(base + (size_t)r * H))[lane];
    float o0f = fmaf(s, acc.x, b2f(b.x));
    float o1f = fmaf(s, acc.y, b2f(b.y));
    float o2f = fmaf(s, acc.z, b2f(b.z));
    float o3f = fmaf(s, acc.w, b2f(b.w));
    ushort4 pk;
    pk.x = f2b(o0f); pk.y = f2b(o1f); pk.z = f2b(o2f); pk.w = f2b(o3f);
    ((ushort4*)(dst + (size_t)r * H))[lane] = pk;
    if (m8) m8[(size_t)r * 64 + lane] = pk4_fp8(o0f, o1f, o2f, o3f);
}

// ---------------- reductions / head (parallelized) ----------------
__global__ __launch_bounds__(256) void colsum_slots(
    const u16* __restrict__ embA, const u16* __restrict__ embB,
    float* __restrict__ part, int N)
{
    int blk = blockIdx.x;
    const u16* emb = (blk < 256) ? embA : embB;
    int rb = blk & 255;
    int c = threadIdx.x;
    float s = 0.f;
    for (int r = rb; r < N; r += 256)
        s += b2f(emb[(size_t)r * H + c]);
    part[(size_t)blk * H + c] = s;
}

__global__ __launch_bounds__(256) void head_comb(
    const float* __restrict__ part, float invNT, float invNE,
    const float* __restrict__ ta_w, const float* __restrict__ ta_b,
    const float* __restrict__ ea_w, const float* __restrict__ ea_b,
    float* __restrict__ comb)
{
    __shared__ float mean[H];
    __shared__ float red[32][8];
    int blk = blockIdx.x;
    int side = blk >> 3;
    int c0 = (blk & 7) * 32;
    int t = threadIdx.x;
    const float* p = part + (side ? (size_t)256 * H : 0);
    float s = 0.f;
    for (int b = 0; b < 256; b++) s += p[(size_t)b * H + t];
    mean[t] = s * (side ? invNE : invNT);
    __syncthreads();
    const float* W = side ? ea_w : ta_w;
    const float* bb = side ? ea_b : ta_b;
    int c = t & 31, g = t >> 5;
    float acc = 0.f;
    for (int k = g * 32; k < g * 32 + 32; k++)
        acc += mean[k] * W[k * H + (c0 + c)];
    red[c][g] = acc;
    __syncthreads();
    if (t < 32) {
        float v = 0.f;
        #pragma unroll
        for (int g2 = 0; g2 < 8; g2++) v += red[t][g2];
        comb[side * H + c0 + t] = fmaxf(v + bb[c0 + t], 0.f);
    }
}

__global__ __launch_bounds__(256) void head_hid(
    const float* __restrict__ comb, const float* __restrict__ ow1,
    const float* __restrict__ ob1, float* __restrict__ hid)
{
    __shared__ float cb[2 * H];
    __shared__ float red[32][8];
    int c0 = blockIdx.x * 32;
    int t = threadIdx.x;
    cb[t] = comb[t];
    cb[t + H] = comb[t + H];
    __syncthreads();
    int c = t & 31, g = t >> 5;
    float acc = 0.f;
    for (int k = g * 64; k < g * 64 + 64; k++)
        acc += cb[k] * ow1[k * H + (c0 + c)];
    red[c][g] = acc;
    __syncthreads();
    if (t < 32) {
        float v = 0.f;
        #pragma unroll
        for (int g2 = 0; g2 < 8; g2++) v += red[t][g2];
        hid[c0 + t] = fmaxf(v + ob1[c0 + t], 0.f);
    }
}

__global__ __launch_bounds__(256) void head_out(
    const float* __restrict__ hid, const float* __restrict__ ow2,
    const float* __restrict__ ob2, float* __restrict__ out)
{
    __shared__ float hb[H];
    __shared__ float red[32][8];
    int c0 = blockIdx.x * 32;
    int t = threadIdx.x;
    hb[t] = hid[t];
    __syncthreads();
    int c = t & 31, g = t >> 5;
    float acc = 0.f;
    for (int k = g * 32; k < g * 32 + 32; k++)
        acc += hb[k] * ow2[k * H + (c0 + c)];
    red[c][g] = acc;
    __syncthreads();
    if (t < 32) {
        float v = 0.f;
        #pragma unroll
        for (int g2 = 0; g2 < 8; g2++) v += red[t][g2];
        out[c0 + t] = v + ob2[c0 + t];
    }
}

extern "C" void kernel_launch(void* const* d_in, const int* in_sizes, int n_in,
                              void* d_out, int out_size, void* d_ws, size_t ws_size,
                              hipStream_t stream) {
    const float* tf  = (const float*)d_in[0];
    const float* ef  = (const float*)d_in[1];
    const int*   qe  = (const int*)d_in[2];
    const int*   te  = (const int*)d_in[3];
    const int*   ae  = (const int*)d_in[4];
    const int*   pe  = (const int*)d_in[5];
    const float* te_w1 = (const float*)d_in[6];  const float* te_b1 = (const float*)d_in[7];
    const float* te_w2 = (const float*)d_in[8];  const float* te_b2 = (const float*)d_in[9];
    const float* ee_w1 = (const float*)d_in[10]; const float* ee_b1 = (const float*)d_in[11];
    const float* ee_w2 = (const float*)d_in[12]; const float* ee_b2 = (const float*)d_in[13];
    const float* gw0 = (const float*)d_in[14];   const float* gb0 = (const float*)d_in[15];
    const float* gw1 = (const float*)d_in[16];   const float* gb1 = (const float*)d_in[17];
    const float* ta_w = (const float*)d_in[18];  const float* ta_b = (const float*)d_in[19];
    const float* ea_w = (const float*)d_in[20];  const float* ea_b = (const float*)d_in[21];
    const float* ow1 = (const float*)d_in[22];   const float* ob1 = (const float*)d_in[23];
    const float* ow2 = (const float*)d_in[24];   const float* ob2 = (const float*)d_in[25];

    const size_t NB = (size_t)NT * H;
    u16* T  = (u16*)d_ws;            // task emb (post-GNN)
    u16* Bf = T + NB;                // edge emb -> final edge emb
    u16* S  = Bf + NB;               // [fp8 queue sums] -> final task emb
    u16* F  = S + NB;                // GNN input (T+0.5S) -> e_new scratch
    u32* S8 = (u32*)S;               // fp8 queue sums (dead before task2 writes S)
    float* sumpad = (float*)(F + NB);
    int* off5   = (int*)(sumpad + 2 * H);              // 5*(NT+1)
    int* csr5   = off5 + 5 * (NT + 1);                 // 5*NE
    int* counts = csr5 + (size_t)5 * NE;               // CSR scratch (NOT aliased)
    int* starts = counts + (size_t)5 * NBLK * NBKT;
    int* bases  = starts + (size_t)5 * NBLK * NBKT;    // 5*(NBKT+1)
    // fp8 mirrors (NB bytes each)
    u32* M0 = (u32*)(((size_t)(bases + 5 * (NBKT + 1)) + 15) & ~(size_t)15);
    u32* M1 = M0 + NB / 4;
    u32* M2 = M1 + NB / 4;
    u32* M3 = M2 + NB / 4;
    u32* M4 = M3 + NB / 4;
    float* part = (float*)(M4 + NB / 4);               // 512*256 floats
    u16* warena = (u16*)(((size_t)(part + 512 * 256) + 15) & ~(size_t)15);
    u16* wt_te1_h = warena + 0;      u16* wt_te1_l = warena + 16384;
    u16* wt_te2_h = warena + 32768;  u16* wt_te2_l = warena + 98304;
    u16* wt_g0_h  = warena + 163840; u16* wt_g0_l  = warena + 229376;
    u16* wt_g1_h  = warena + 294912; u16* wt_g1_l  = warena + 360448;
    u16* wt_ee1_h = warena + 425984; u16* wt_ee1_l = warena + 442368;
    u16* wt_ee2_h = warena + 458752; u16* wt_ee2_l = warena + 524288;
    float* comb = (float*)(warena + 589824);           // 512 f32
    float* hidb = comb + 2 * H;                        // 256 f32

    const int MG = (NT + 63) / 64;                     // 782
    const int GB = (NT * 64) / 256;                    // 12500
    const int NPART = NBLK * 5;                        // 615
    const int NBUCK = NBKT * 5;                        // 1955

    const int *k0 = qe + NE, *k1 = te + NE, *k2 = ae,      *k3 = ae + NE, *k4 = pe + NE;
    const int *v0 = qe,      *v1 = te,      *v2 = ae + NE, *v3 = ae,      *v4 = pe;

    // ---- weight pack + CSR P1/P2 ----
    wt_pack<<<dim3(256, 6), 256, 0, stream>>>(te_w1, te_w2, gw0, gw1, ee_w1, ee_w2, warena);
    hist_kernel<<<dim3(NBLK, 5), 256, 0, stream>>>(k0, k1, k2, k3, k4, counts);
    scan_buckets<<<5, 256, 0, stream>>>(counts, starts, bases);

    // ---- combo 1: partition ∥ task encoder (-> T, M0) ----
    part_enc<<<NPART + MG, 256, 0, stream>>>(
        k0, k1, k2, k3, k4, v0, v1, v2, v3, v4, starts, csr5,
        tf, wt_te1_h, wt_te1_l, te_b1, wt_te2_h, wt_te2_l, te_b2, T, M0, NT, NPART);

    // ---- combo 2: bucket_csr ∥ edge encoder (-> Bf, M2) ----
    buck_enc<<<NBUCK + MG, 256, 0, stream>>>(
        bases, csr5, off5,
        ef, wt_ee1_h, wt_ee1_l, ee_b1, wt_ee2_h, wt_ee2_l, ee_b2, Bf, M2, NT, NBUCK);

    #define LOFF(l) (off5 + (l) * (NT + 1))
    #define LCSR(l) (csr5 + (size_t)(l) * NE)

    // ---- queue conv: S8 = fp8(segsum(M0[qs] by qt)); F = T + 0.5*sum ----
    gather_q_f8<<<GB, 256, 0, stream>>>(M0, LCSR(0), LOFF(0), T, S8, F, 0.5f, NT);

    // ---- GNN (fused 2 layers): X=F, L1 epilogue +0.5*S8 -> T (+ M1) ----
    fused_mlp<256><<<MG, 256, 0, stream>>>(
        F, S8, wt_g0_h, wt_g0_l, gb0, wt_g1_h, wt_g1_l, gb1, T, M1, NT, 0.5f);

    // ---- fused type + affinity-t (serial dual pipelines): S, M3 ----
    gather_task2<<<GB, 256, 0, stream>>>(
        M1, LCSR(1), LOFF(1), M2, LCSR(2), LOFF(2), T, S, M3, NT);

    // ---- affinity-e: F = Bf + 0.3*mean(M3[asrc] by atgt) (+ M4) ----
    gather_mean_f8<<<GB, 256, 0, stream>>>(
        M3, LCSR(3), LOFF(3), Bf, F, M4, 0.3f, NT);

    // ---- topology: Bf = F + 0.3*mean(M4[ps] by pt) ----
    gather_mean_f8<<<GB, 256, 0, stream>>>(
        M4, LCSR(4), LOFF(4), F, Bf, nullptr, 0.3f, NT);

    // ---- aggregation + head (task = S, edge = Bf), parallel head ----
    colsum_slots<<<512, 256, 0, stream>>>(S, Bf, part, NT);
    head_comb<<<16, 256, 0, stream>>>(part, 1.f / NT, 1.f / NEDGE,
                                      ta_w, ta_b, ea_w, ea_b, comb);
    head_hid<<<8, 256, 0, stream>>>(comb, ow1, ob1, hidb);
    head_out<<<8, 256, 0, stream>>>(hidb, ow2, ob2, (float*)d_out);
}